// Round 7
// baseline (255.321 us; speedup 1.0000x reference)
//
#include <hip/hip_runtime.h>
#include <hip/hip_bf16.h>

typedef __bf16 bf16_t;
typedef __bf16 bf16x4 __attribute__((ext_vector_type(4)));
typedef __bf16 bf16x8 __attribute__((ext_vector_type(8)));
typedef float f32x4 __attribute__((ext_vector_type(4)));

#define MFMA16(a, b, c) __builtin_amdgcn_mfma_f32_16x16x32_bf16((a), (b), (c), 0, 0, 0)

// async global->LDS, 16B per lane; dest = wave-uniform base + lane*16
__device__ __forceinline__ void gl16(const bf16_t* g, void* l) {
    __builtin_amdgcn_global_load_lds(
        (const __attribute__((address_space(1))) void*)g,
        (__attribute__((address_space(3))) void*)l, 16, 0, 0);
}

// Problem constants
// B=16, C=192, H=W=56, WIN=7, SHIFT=3, HEADS=6, DH=32, HID=768
// tokens M = 16*8*8*49 = 50176, windows = 1024

// ---------------- weight convert (4 weights -> contiguous bf16) ----------
__global__ __launch_bounds__(256) void k_cvt(const float* __restrict__ qkvw,
                                             const float* __restrict__ projw,
                                             const float* __restrict__ fc1w,
                                             const float* __restrict__ fc2w,
                                             bf16_t* __restrict__ dst)
{
    int i = blockIdx.x * 256 + threadIdx.x;
    if (i >= 442368) return;
    float v;
    if (i < 110592)      v = qkvw[i];
    else if (i < 147456) v = projw[i - 110592];
    else if (i < 294912) v = fc1w[i - 147456];
    else                 v = fc2w[i - 294912];
    dst[i] = (bf16_t)v;
}

// ---------------- LN1 + roll(-3) + window partition -> xw bf16 -----------
__global__ __launch_bounds__(1024) void k_ln1(const float* __restrict__ x,
                                              const float* __restrict__ gam,
                                              const float* __restrict__ bet,
                                              bf16_t* __restrict__ xw)
{
    __shared__ float tile[56][193];     // odd stride: conflict-free row reads
    __shared__ bf16_t obuf[56 * 192];   // row stride 384B = 24 int4
    const int bh = blockIdx.x;
    const int b = bh / 56, h = bh % 56;
    const int tid = threadIdx.x;

    // phase 1: x[b][:][h][:] -> tile[w][c] (float4 global loads)
    {
        const int g = tid >> 4, u = tid & 15;   // g: channel group 0..63
        const float* xb = x + (long)b * 602112 + (long)h * 56;
        if (u < 14) {
            #pragma unroll
            for (int k = 0; k < 3; ++k) {
                const int c = g + 64 * k;
                float4 v = *(const float4*)(xb + (long)c * 3136 + u * 4);
                tile[u * 4 + 0][c] = v.x;
                tile[u * 4 + 1][c] = v.y;
                tile[u * 4 + 2][c] = v.z;
                tile[u * 4 + 3][c] = v.w;
            }
        }
    }
    __syncthreads();

    // phase 2: LN per token (wave-parallel over w), bf16 -> obuf by rolled idx
    const int wave = tid >> 6, lane = tid & 63;
    const float g0 = gam[lane], g1 = gam[lane + 64], g2 = gam[lane + 128];
    const float b0 = bet[lane], b1 = bet[lane + 64], b2 = bet[lane + 128];
    for (int wp = wave; wp < 56; wp += 16) {
        float v0 = tile[wp][lane], v1 = tile[wp][lane + 64], v2 = tile[wp][lane + 128];
        float s = v0 + v1 + v2;
        float sq = v0 * v0 + v1 * v1 + v2 * v2;
        #pragma unroll
        for (int d = 1; d < 64; d <<= 1) { s += __shfl_xor(s, d); sq += __shfl_xor(sq, d); }
        float mean = s * (1.f / 192.f);
        float var  = sq * (1.f / 192.f) - mean * mean;
        float rs = rsqrtf(var + 1e-5f);
        const int wr = (wp + 53) % 56;
        bf16_t* o = obuf + wr * 192;
        o[lane]       = (bf16_t)((v0 - mean) * rs * g0 + b0);
        o[lane + 64]  = (bf16_t)((v1 - mean) * rs * g1 + b1);
        o[lane + 128] = (bf16_t)((v2 - mean) * rs * g2 + b2);
    }
    __syncthreads();

    // phase 3: obuf -> xw, 8 window-groups x 7 contiguous rows (int4 stores)
    const int hr = (h + 53) % 56;
    const int nh = hr / 7, ii = hr % 7;
    const long rband = ((long)b * 64 + (long)nh * 8) * 49 + (long)ii * 7;
    const int4* src = (const int4*)obuf;
    for (int q = tid; q < 1344; q += 1024) {
        const int g = q / 168, u = q % 168;
        const int jj = u / 24, ci = u % 24;
        const long r = rband + (long)g * 49 + jj;
        ((int4*)xw)[r * 24 + ci] = src[(g * 7 + jj) * 24 + ci];
    }
}

// ---- W-stationary GEMM for K=192: W-slice in registers, A streamed ------
// Block: 4 waves, each wave owns 8 independent chunks of 16 rows.
// No barriers in the hot loop; A double-buffered in regs.
// grid = (N/64, 98);  EPI: 0 = bf16 out, 2 = bf16 out + tanh-GELU
template<int EPI, int N>
__global__ __launch_bounds__(256) void k_gemm_ws(const bf16_t* __restrict__ A,
                                                 const bf16_t* __restrict__ W,
                                                 const float* __restrict__ bias,
                                                 bf16_t* __restrict__ outp)
{
    __shared__ bf16_t Wl[64 * 200];   // rows padded to 400B (25.6 KB)
    const int tid = threadIdx.x;
    const int wv = tid >> 6, ln = tid & 63;
    const int lrow = ln & 15, lkg = ln >> 4;
    const int n0 = blockIdx.x * 64;

    // prologue: stage W[n0..n0+64)[0..192) into padded LDS
    {
        const int4* ws4 = (const int4*)(W + (long)n0 * 192);   // contiguous 24576B
        #pragma unroll
        for (int i = 0; i < 6; ++i) {
            const int e = tid + i * 256;            // int4 index 0..1535
            const int row = e / 24, c16 = e % 24;
            *(int4*)((char*)Wl + row * 400 + c16 * 16) = ws4[e];
        }
    }
    __syncthreads();

    // W frags -> registers: wf[ni][kk]; lane: lrow = n-row, lkg = k-subgroup
    bf16x8 wf[4][6];
    #pragma unroll
    for (int ni = 0; ni < 4; ++ni)
        #pragma unroll
        for (int kk = 0; kk < 6; ++kk)
            wf[ni][kk] = *(const bf16x8*)((const char*)Wl
                          + (ni * 16 + lrow) * 400 + kk * 64 + lkg * 16);

    float4 bv[4];
    #pragma unroll
    for (int ni = 0; ni < 4; ++ni)
        bv[ni] = *(const float4*)(bias + n0 + ni * 16 + lkg * 4);

    // wave's A stream: rows [ws*128, ws*128+128), this lane reads row +lrow
    const long row0 = ((long)blockIdx.y * 4 + wv) * 128 + lrow;
    const bf16_t* ap = A + row0 * 192 + lkg * 8;

    auto compute_store = [&](bf16x8 (&af)[6], int c) {
        f32x4 acc[4];
        #pragma unroll
        for (int ni = 0; ni < 4; ++ni)
            #pragma unroll
            for (int rg = 0; rg < 4; ++rg) acc[ni][rg] = 0.f;
        #pragma unroll
        for (int kk = 0; kk < 6; ++kk)
            #pragma unroll
            for (int ni = 0; ni < 4; ++ni)
                acc[ni] = MFMA16(wf[ni][kk], af[kk], acc[ni]);
        const long m = row0 + c * 16;
        #pragma unroll
        for (int ni = 0; ni < 4; ++ni) {
            float v[4] = { acc[ni][0] + bv[ni].x, acc[ni][1] + bv[ni].y,
                           acc[ni][2] + bv[ni].z, acc[ni][3] + bv[ni].w };
            bf16x4 o;
            #pragma unroll
            for (int rg = 0; rg < 4; ++rg) {
                float u = v[rg];
                if (EPI == 2) {
                    float t2 = fminf(u * (1.5957691216057308f
                                          + 0.07135481627f * u * u), 60.f);
                    float e = __expf(t2);
                    u = u * e / (e + 1.f);
                }
                o[rg] = (bf16_t)u;
            }
            *(bf16x4*)(outp + m * N + n0 + ni * 16 + lkg * 4) = o;
        }
    };

    bf16x8 a0[6], a1[6];
    #pragma unroll
    for (int kk = 0; kk < 6; ++kk) a0[kk] = *(const bf16x8*)(ap + kk * 32);

    #pragma unroll
    for (int c = 0; c < 8; c += 2) {
        #pragma unroll
        for (int kk = 0; kk < 6; ++kk)
            a1[kk] = *(const bf16x8*)(ap + (long)(c + 1) * 3072 + kk * 32);
        compute_store(a0, c);
        if (c + 2 < 8) {
            #pragma unroll
            for (int kk = 0; kk < 6; ++kk)
                a0[kk] = *(const bf16x8*)(ap + (long)(c + 2) * 3072 + kk * 32);
        }
        compute_store(a1, c + 1);
    }
}

// ---------------- GEMM (barrier pipeline) — used for fc2 (K=768) ---------
template<int EPI, int N, int K, int G>
__global__ __launch_bounds__(256) void k_gemm(const bf16_t* __restrict__ A,
                                              const bf16_t* __restrict__ W,
                                              const float* __restrict__ bias,
                                              bf16_t* __restrict__ outp)
{
    constexpr int NT = K / 64;          // K-steps per M-tile
    constexpr int NS = G * NT;          // total pipeline steps
    __shared__ bf16_t As[2][128 * 64];  // 2 x 16 KB
    __shared__ bf16_t Bs[2][64 * 64];   // 2 x 8 KB
    const int tid = threadIdx.x;
    const int wv = tid >> 6, ln = tid & 63;
    const int lrow = ln & 15, lkg = ln >> 4;
    const int r7 = lrow & 7;
    const int wm = (wv >> 1) * 64, wn = (wv & 1) * 32;
    const long bm0 = (long)blockIdx.x * (G * 128);
    const int n0 = blockIdx.y * 64;

    int arow[4], acol[4];
    #pragma unroll
    for (int i = 0; i < 4; ++i) {
        const int off = ((wv * 4 + i) << 10) + ln * 16;
        arow[i] = off >> 7;
        acol[i] = (((off >> 4) & 7) ^ (arow[i] & 7)) << 3;
    }
    int brow[2], bcol[2];
    #pragma unroll
    for (int i = 0; i < 2; ++i) {
        const int off = ((wv * 2 + i) << 10) + ln * 16;
        brow[i] = off >> 7;
        bcol[i] = (((off >> 4) & 7) ^ (brow[i] & 7)) << 3;
    }

    f32x4 acc[4][2];
    #pragma unroll
    for (int mi = 0; mi < 4; ++mi)
        #pragma unroll
        for (int ni = 0; ni < 2; ++ni)
            #pragma unroll
            for (int rg = 0; rg < 4; ++rg) acc[mi][ni][rg] = 0.f;

    auto stage = [&](int buf, int g, int t) {
        const long ab = (bm0 + (long)(g << 7)) * K + t * 64;
        #pragma unroll
        for (int i = 0; i < 4; ++i)
            gl16(A + ab + arow[i] * K + acol[i],
                 (char*)As[buf] + ((wv * 4 + i) << 10));
        #pragma unroll
        for (int i = 0; i < 2; ++i)
            gl16(W + (long)(n0 + brow[i]) * K + t * 64 + bcol[i],
                 (char*)Bs[buf] + ((wv * 2 + i) << 10));
    };

    auto compute = [&](int buf) {
        #pragma unroll
        for (int kk = 0; kk < 2; ++kk) {
            bf16x8 af[4], bfr[2];
            #pragma unroll
            for (int mi = 0; mi < 4; ++mi) {
                const int row = wm + mi * 16 + lrow;
                af[mi] = *(const bf16x8*)((const char*)As[buf] + row * 128
                           + ((((kk << 2) | lkg) ^ r7) << 4));
            }
            #pragma unroll
            for (int ni = 0; ni < 2; ++ni) {
                const int row = wn + ni * 16 + lrow;
                bfr[ni] = *(const bf16x8*)((const char*)Bs[buf] + row * 128
                           + ((((kk << 2) | lkg) ^ r7) << 4));
            }
            #pragma unroll
            for (int mi = 0; mi < 4; ++mi)
                #pragma unroll
                for (int ni = 0; ni < 2; ++ni)
                    acc[mi][ni] = MFMA16(bfr[ni], af[mi], acc[mi][ni]); // swapped
        }
    };

    stage(0, 0, 0);
    __syncthreads();
    int cur = 0;
    #pragma unroll
    for (int g = 0; g < G; ++g) {
        #pragma unroll
        for (int t = 0; t < NT; ++t) {
            const int s = g * NT + t;
            if (s + 1 < NS) {
                const int t1 = (t + 1 == NT) ? 0 : t + 1;
                const int g1 = (t + 1 == NT) ? g + 1 : g;
                stage(cur ^ 1, g1, t1);
            }
            compute(cur);
            if (t == NT - 1) {
                #pragma unroll
                for (int mi = 0; mi < 4; ++mi) {
                    const long m = bm0 + (g << 7) + wm + mi * 16 + lrow;
                    #pragma unroll
                    for (int ni = 0; ni < 2; ++ni) {
                        const int nb = n0 + wn + ni * 16 + lkg * 4;
                        const float4 bvv = *(const float4*)(bias + nb);
                        float v[4] = { acc[mi][ni][0] + bvv.x, acc[mi][ni][1] + bvv.y,
                                       acc[mi][ni][2] + bvv.z, acc[mi][ni][3] + bvv.w };
                        bf16x4 o;
                        #pragma unroll
                        for (int rg = 0; rg < 4; ++rg) {
                            float u = v[rg];
                            if (EPI == 2) {
                                float t2 = fminf(u * (1.5957691216057308f
                                                      + 0.07135481627f * u * u), 60.f);
                                float e = __expf(t2);
                                u = u * e / (e + 1.f);
                            }
                            o[rg] = (bf16_t)u;
                        }
                        *(bf16x4*)(outp + m * N + nb) = o;
                        #pragma unroll
                        for (int rg = 0; rg < 4; ++rg) acc[mi][ni][rg] = 0.f;
                    }
                }
            }
            __syncthreads();
            cur ^= 1;
        }
    }
}

// ------- proj GEMM (N=192, K=192) with fused LN2 epilogue -> bf16 --------
__global__ __launch_bounds__(256) void k_proj_ln(const bf16_t* __restrict__ A,
                                                 const bf16_t* __restrict__ W,
                                                 const float* __restrict__ bias,
                                                 const float* __restrict__ gam,
                                                 const float* __restrict__ bet,
                                                 bf16_t* __restrict__ out)
{
    __shared__ bf16_t As[128][72];   // 18 KB
    __shared__ bf16_t Bs[192][72];   // 27 KB
    const int tid = threadIdx.x;
    const int wave = tid >> 6, lane = tid & 63;
    const int lrow = lane & 15, lkg = lane >> 4;
    const int wm = wave * 32;
    const long m0 = (long)blockIdx.x * 128;

    f32x4 acc[2][12];
    #pragma unroll
    for (int mi = 0; mi < 2; ++mi)
        #pragma unroll
        for (int ni = 0; ni < 12; ++ni)
            #pragma unroll
            for (int rg = 0; rg < 4; ++rg) acc[mi][ni][rg] = 0.f;

    for (int k0 = 0; k0 < 192; k0 += 64) {
        #pragma unroll
        for (int it = 0; it < 4; ++it) {
            int e = (tid + it * 256) * 8;
            int r = e >> 6, c = e & 63;
            *(int4*)(&As[r][c]) = *(const int4*)(A + (m0 + r) * 192 + (k0 + c));
        }
        #pragma unroll
        for (int it = 0; it < 6; ++it) {
            int e = (tid + it * 256) * 8;
            int r = e >> 6, c = e & 63;
            *(int4*)(&Bs[r][c]) = *(const int4*)(W + (long)r * 192 + (k0 + c));
        }
        __syncthreads();
        #pragma unroll
        for (int kk = 0; kk < 64; kk += 32) {
            bf16x8 af[2];
            #pragma unroll
            for (int mi = 0; mi < 2; ++mi)
                af[mi] = *(const bf16x8*)(&As[wm + mi * 16 + lrow][kk + lkg * 8]);
            #pragma unroll
            for (int ni = 0; ni < 12; ++ni) {
                bf16x8 bfr = *(const bf16x8*)(&Bs[ni * 16 + lrow][kk + lkg * 8]);
                acc[0][ni] = MFMA16(af[0], bfr, acc[0][ni]);
                acc[1][ni] = MFMA16(af[1], bfr, acc[1][ni]);
            }
        }
        __syncthreads();
    }

    float bv[12];
    #pragma unroll
    for (int ni = 0; ni < 12; ++ni) bv[ni] = bias[ni * 16 + lrow];

    #pragma unroll
    for (int mi = 0; mi < 2; ++mi) {
        #pragma unroll
        for (int rg = 0; rg < 4; ++rg) {
            float val[12];
            float s = 0.f, sq = 0.f;
            #pragma unroll
            for (int ni = 0; ni < 12; ++ni) {
                val[ni] = acc[mi][ni][rg] + bv[ni];
                s += val[ni];
                sq += val[ni] * val[ni];
            }
            #pragma unroll
            for (int d = 1; d < 16; d <<= 1) {
                s += __shfl_xor(s, d);
                sq += __shfl_xor(sq, d);
            }
            float mean = s * (1.f / 192.f);
            float var  = sq * (1.f / 192.f) - mean * mean;
            float rs = rsqrtf(var + 1e-5f);
            const long row = m0 + wm + mi * 16 + lkg * 4 + rg;
            bf16_t* orow = out + row * 192;
            #pragma unroll
            for (int ni = 0; ni < 12; ++ni) {
                const int col = ni * 16 + lrow;
                orow[col] = (bf16_t)((val[ni] - mean) * rs * gam[col] + bet[col]);
            }
        }
    }
}

// ---------------- window attention: 1 wave per (window, head) ------------
__global__ __launch_bounds__(64) void k_attn(const bf16_t* __restrict__ qkv,
                                             bf16_t* __restrict__ aout)
{
    __shared__ bf16_t Pl[64][72];
    __shared__ bf16_t Vt[32][72];   // V transposed: Vt[d][m]
    const int win = blockIdx.x, head = blockIdx.y;
    const int lane = threadIdx.x;
    const int lrow = lane & 15, lkg = lane >> 4;
    const bf16_t* base = qkv + (long)win * 28224 + head * 32;  // 49*576

    // stage V^T into LDS (rows m>=49 zeroed)
    {
        const int m = lane;
        const int mc = (m < 49) ? m : 48;
        const int4* vr = (const int4*)(base + (long)mc * 576 + 384);
        #pragma unroll
        for (int c4 = 0; c4 < 4; ++c4) {
            int4 vv = vr[c4];
            if (m >= 49) vv = make_int4(0, 0, 0, 0);
            const bf16_t* pe = (const bf16_t*)&vv;
            #pragma unroll
            for (int e = 0; e < 8; ++e) Vt[c4 * 8 + e][m] = pe[e];
        }
    }

    // QK^T: S[n][m] = sum_d q[n][d] k[m][d], padded 49->64
    bf16x8 z8;
    #pragma unroll
    for (int e = 0; e < 8; ++e) z8[e] = (bf16_t)0.f;
    bf16x8 qf[4], kf[4];
    #pragma unroll
    for (int t = 0; t < 4; ++t) {
        const int n = t * 16 + lrow;
        const int nc = (n < 49) ? n : 48;
        bf16x8 qv = *(const bf16x8*)(base + (long)nc * 576 + lkg * 8);
        bf16x8 kv = *(const bf16x8*)(base + (long)nc * 576 + 192 + lkg * 8);
        qf[t] = (n < 49) ? qv : z8;
        kf[t] = (n < 49) ? kv : z8;
    }
    f32x4 zf; zf[0] = zf[1] = zf[2] = zf[3] = 0.f;
    f32x4 S[4][4];
    #pragma unroll
    for (int mi = 0; mi < 4; ++mi)
        #pragma unroll
        for (int mj = 0; mj < 4; ++mj)
            S[mi][mj] = MFMA16(qf[mi], kf[mj], zf);

    // row softmax (cols >= 49 masked), P -> LDS as bf16
    const float scl = 0.17677669529663687f;   // 32^-0.5
    #pragma unroll
    for (int mi = 0; mi < 4; ++mi) {
        #pragma unroll
        for (int rg = 0; rg < 4; ++rg) {
            float v0 = S[mi][0][rg] * scl;
            float v1 = S[mi][1][rg] * scl;
            float v2 = S[mi][2][rg] * scl;
            float v3 = (lrow == 0) ? S[mi][3][rg] * scl : -1e30f;  // col 48+lrow
            float mx = fmaxf(fmaxf(v0, v1), fmaxf(v2, v3));
            #pragma unroll
            for (int d = 1; d < 16; d <<= 1) mx = fmaxf(mx, __shfl_xor(mx, d));
            float e0 = expf(v0 - mx), e1 = expf(v1 - mx), e2 = expf(v2 - mx);
            float e3 = (lrow == 0) ? expf(v3 - mx) : 0.f;
            float sm = e0 + e1 + e2 + e3;
            #pragma unroll
            for (int d = 1; d < 16; d <<= 1) sm += __shfl_xor(sm, d);
            float is = 1.f / sm;
            const int row = mi * 16 + lkg * 4 + rg;
            Pl[row][lrow]      = (bf16_t)(e0 * is);
            Pl[row][16 + lrow] = (bf16_t)(e1 * is);
            Pl[row][32 + lrow] = (bf16_t)(e2 * is);
            Pl[row][48 + lrow] = (bf16_t)(e3 * is);
        }
    }
    __syncthreads();

    // PV: out[n][d] = sum_m P[n][m] Vt[d][m]
    f32x4 o[4][2];
    #pragma unroll
    for (int ni = 0; ni < 4; ++ni)
        #pragma unroll
        for (int di = 0; di < 2; ++di)
            #pragma unroll
            for (int rg = 0; rg < 4; ++rg) o[ni][di][rg] = 0.f;
    #pragma unroll
    for (int m0 = 0; m0 < 64; m0 += 32) {
        bf16x8 pf[4], vf[2];
        #pragma unroll
        for (int ni = 0; ni < 4; ++ni)
            pf[ni] = *(const bf16x8*)(&Pl[ni * 16 + lrow][m0 + lkg * 8]);
        #pragma unroll
        for (int di = 0; di < 2; ++di)
            vf[di] = *(const bf16x8*)(&Vt[di * 16 + lrow][m0 + lkg * 8]);
        #pragma unroll
        for (int ni = 0; ni < 4; ++ni)
            #pragma unroll
            for (int di = 0; di < 2; ++di)
                o[ni][di] = MFMA16(pf[ni], vf[di], o[ni][di]);
    }
    #pragma unroll
    for (int ni = 0; ni < 4; ++ni) {
        #pragma unroll
        for (int rg = 0; rg < 4; ++rg) {
            const int n = ni * 16 + lkg * 4 + rg;
            if (n < 49) {
                bf16_t* orow = aout + ((long)win * 49 + n) * 192 + head * 32;
                orow[lrow]      = (bf16_t)o[ni][0][rg];
                orow[16 + lrow] = (bf16_t)o[ni][1][rg];
            }
        }
    }
}

// ---------------- final: un-window + roll(+3) + BHWC->BCHW + shortcut ----
__global__ __launch_bounds__(1024) void k_final(const bf16_t* __restrict__ fb,
                                                const float* __restrict__ x,
                                                float* __restrict__ out)
{
    __shared__ float tile[56][199];   // odd-ish stride: conflict-free col reads
    const int bh = blockIdx.x;
    const int b = bh / 56, hq = bh % 56;
    const int tid = threadIdx.x;
    const int hr = (hq + 53) % 56;
    const int nh = hr / 7, ii = hr % 7;
    const long rband = ((long)b * 64 + (long)nh * 8) * 49 + (long)ii * 7;

    // phase 1: gather fb rows (contiguous 384B/row) into tile[wq][c]
    for (int q = tid; q < 1344; q += 1024) {
        const int g = q / 168, rem = q % 168;
        const int jj = rem / 24, ci = rem % 24;
        const long rr = rband + (long)g * 49 + jj;
        bf16x8 v = *(const bf16x8*)(fb + rr * 192 + ci * 8);
        const int wq = (g * 7 + jj + 3) % 56;
        #pragma unroll
        for (int e = 0; e < 8; ++e) tile[wq][ci * 8 + e] = (float)v[e];
    }
    __syncthreads();

    // phase 2: out[b][c][hq][w] = tile[w][c] + x[b][c][hq][w]  (float4 along w)
    const int g = tid >> 4, u = tid & 15;
    if (u < 14) {
        #pragma unroll
        for (int k = 0; k < 3; ++k) {
            const int c = g + 64 * k;
            const long base = ((long)b * 192 + c) * 3136 + (long)hq * 56 + u * 4;
            float4 xv = *(const float4*)(x + base);
            float4 ov;
            ov.x = tile[u * 4 + 0][c] + xv.x;
            ov.y = tile[u * 4 + 1][c] + xv.y;
            ov.z = tile[u * 4 + 2][c] + xv.z;
            ov.w = tile[u * 4 + 3][c] + xv.w;
            *(float4*)(out + base) = ov;
        }
    }
}

extern "C" void kernel_launch(void* const* d_in, const int* in_sizes, int n_in,
                              void* d_out, int out_size, void* d_ws, size_t ws_size,
                              hipStream_t stream)
{
    const float* x     = (const float*)d_in[0];
    const float* n1w   = (const float*)d_in[1];
    const float* n1b   = (const float*)d_in[2];
    const float* qkvw  = (const float*)d_in[3];
    const float* qkvb  = (const float*)d_in[4];
    const float* projw = (const float*)d_in[5];
    const float* projb = (const float*)d_in[6];
    const float* n2w   = (const float*)d_in[7];
    const float* n2b   = (const float*)d_in[8];
    const float* fc1w  = (const float*)d_in[9];
    const float* fc1b  = (const float*)d_in[10];
    const float* fc2w  = (const float*)d_in[11];
    const float* fc2b  = (const float*)d_in[12];

    char* ws = (char*)d_ws;
    bf16_t* wqkv  = (bf16_t*)(ws);              // 576*192  bf16
    bf16_t* wproj = (bf16_t*)(ws + 221184);     // 192*192
    bf16_t* wfc1  = (bf16_t*)(ws + 294912);     // 768*192
    bf16_t* wfc2  = (bf16_t*)(ws + 589824);     // 192*768
    bf16_t* Xb    = (bf16_t*)(ws + 884736);     // [50176][192] bf16 (LN1 out, attn out)
    bf16_t* QKV   = (bf16_t*)(ws + 20152320);   // [50176][576] bf16
    bf16_t* Hb    = (bf16_t*)(ws + 77955072);   // [50176][768] bf16 (fc1 out)
    bf16_t* H2    = (bf16_t*)(ws + 155025408);  // [50176][192] bf16 (fc2 out)
    bf16_t* X2    = (bf16_t*)(ws + 174292992);  // [50176][192] bf16 (LN2 out)

    k_cvt<<<1728, 256, 0, stream>>>(qkvw, projw, fc1w, fc2w, wqkv);
    k_ln1<<<896, 1024, 0, stream>>>(x, n1w, n1b, Xb);
    k_gemm_ws<0, 576><<<dim3(9, 98), 256, 0, stream>>>(Xb, wqkv, qkvb, QKV);
    k_attn<<<dim3(1024, 6), 64, 0, stream>>>(QKV, Xb);
    k_proj_ln<<<392, 256, 0, stream>>>(Xb, wproj, projb, n2w, n2b, X2);
    k_gemm_ws<2, 768><<<dim3(12, 98), 256, 0, stream>>>(X2, wfc1, fc1b, Hb);
    k_gemm<0, 192, 768, 1><<<dim3(392, 3), 256, 0, stream>>>(Hb, wfc2, fc2b, H2);
    k_final<<<896, 1024, 0, stream>>>(H2, x, (float*)d_out);
}

// Round 8
// 244.825 us; speedup vs baseline: 1.0429x; 1.0429x over previous
//
#include <hip/hip_runtime.h>
#include <hip/hip_bf16.h>

typedef __bf16 bf16_t;
typedef __bf16 bf16x4 __attribute__((ext_vector_type(4)));
typedef __bf16 bf16x8 __attribute__((ext_vector_type(8)));
typedef float f32x4 __attribute__((ext_vector_type(4)));

#define MFMA16(a, b, c) __builtin_amdgcn_mfma_f32_16x16x32_bf16((a), (b), (c), 0, 0, 0)

// async global->LDS, 16B per lane; dest = wave-uniform base + lane*16
__device__ __forceinline__ void gl16(const bf16_t* g, void* l) {
    __builtin_amdgcn_global_load_lds(
        (const __attribute__((address_space(1))) void*)g,
        (__attribute__((address_space(3))) void*)l, 16, 0, 0);
}

__device__ __forceinline__ float gelu_t(float u) {
    float t2 = fminf(u * (1.5957691216057308f + 0.07135481627f * u * u), 60.f);
    float e = __expf(t2);
    return u * e / (e + 1.f);
}

// Problem constants
// B=16, C=192, H=W=56, WIN=7, SHIFT=3, HEADS=6, DH=32, HID=768
// tokens M = 16*8*8*49 = 50176, windows = 1024

// ---------------- weight convert (4 weights -> contiguous bf16) ----------
__global__ __launch_bounds__(256) void k_cvt(const float* __restrict__ qkvw,
                                             const float* __restrict__ projw,
                                             const float* __restrict__ fc1w,
                                             const float* __restrict__ fc2w,
                                             bf16_t* __restrict__ dst)
{
    int i = blockIdx.x * 256 + threadIdx.x;
    if (i >= 442368) return;
    float v;
    if (i < 110592)      v = qkvw[i];
    else if (i < 147456) v = projw[i - 110592];
    else if (i < 294912) v = fc1w[i - 147456];
    else                 v = fc2w[i - 294912];
    dst[i] = (bf16_t)v;
}

// ---------------- LN1 + roll(-3) + window partition -> xw bf16 -----------
__global__ __launch_bounds__(1024) void k_ln1(const float* __restrict__ x,
                                              const float* __restrict__ gam,
                                              const float* __restrict__ bet,
                                              bf16_t* __restrict__ xw)
{
    __shared__ float tile[56][193];     // odd stride: conflict-free row reads
    __shared__ bf16_t obuf[56 * 192];   // row stride 384B = 24 int4
    const int bh = blockIdx.x;
    const int b = bh / 56, h = bh % 56;
    const int tid = threadIdx.x;

    // phase 1: x[b][:][h][:] -> tile[w][c] (float4 global loads)
    {
        const int g = tid >> 4, u = tid & 15;   // g: channel group 0..63
        const float* xb = x + (long)b * 602112 + (long)h * 56;
        if (u < 14) {
            #pragma unroll
            for (int k = 0; k < 3; ++k) {
                const int c = g + 64 * k;
                float4 v = *(const float4*)(xb + (long)c * 3136 + u * 4);
                tile[u * 4 + 0][c] = v.x;
                tile[u * 4 + 1][c] = v.y;
                tile[u * 4 + 2][c] = v.z;
                tile[u * 4 + 3][c] = v.w;
            }
        }
    }
    __syncthreads();

    // phase 2: LN per token (wave-parallel over w), bf16 -> obuf by rolled idx
    const int wave = tid >> 6, lane = tid & 63;
    const float g0 = gam[lane], g1 = gam[lane + 64], g2 = gam[lane + 128];
    const float b0 = bet[lane], b1 = bet[lane + 64], b2 = bet[lane + 128];
    for (int wp = wave; wp < 56; wp += 16) {
        float v0 = tile[wp][lane], v1 = tile[wp][lane + 64], v2 = tile[wp][lane + 128];
        float s = v0 + v1 + v2;
        float sq = v0 * v0 + v1 * v1 + v2 * v2;
        #pragma unroll
        for (int d = 1; d < 64; d <<= 1) { s += __shfl_xor(s, d); sq += __shfl_xor(sq, d); }
        float mean = s * (1.f / 192.f);
        float var  = sq * (1.f / 192.f) - mean * mean;
        float rs = rsqrtf(var + 1e-5f);
        const int wr = (wp + 53) % 56;
        bf16_t* o = obuf + wr * 192;
        o[lane]       = (bf16_t)((v0 - mean) * rs * g0 + b0);
        o[lane + 64]  = (bf16_t)((v1 - mean) * rs * g1 + b1);
        o[lane + 128] = (bf16_t)((v2 - mean) * rs * g2 + b2);
    }
    __syncthreads();

    // phase 3: obuf -> xw, 8 window-groups x 7 contiguous rows (int4 stores)
    const int hr = (h + 53) % 56;
    const int nh = hr / 7, ii = hr % 7;
    const long rband = ((long)b * 64 + (long)nh * 8) * 49 + (long)ii * 7;
    const int4* src = (const int4*)obuf;
    for (int q = tid; q < 1344; q += 1024) {
        const int g = q / 168, u = q % 168;
        const int jj = u / 24, ci = u % 24;
        const long r = rband + (long)g * 49 + jj;
        ((int4*)xw)[r * 24 + ci] = src[(g * 7 + jj) * 24 + ci];
    }
}

// ------ wide-tile GEMM: block 128m x 192n, wave 64x96, K compile-time ----
// gl16 staging, linear LDS + XOR-swizzle pair (src pre-swizzle + swz read).
// Swapped MFMA operands: lane holds m=..+lrow, n=..+lkg*4+rg -> bf16x4 store.
// EPI: 0 = bf16 out, 2 = bf16 out + tanh-GELU
template<int EPI, int N, int K>
__global__ __launch_bounds__(256) void k_gemm192(const bf16_t* __restrict__ A,
                                                 const bf16_t* __restrict__ W,
                                                 const float* __restrict__ bias,
                                                 bf16_t* __restrict__ outp)
{
    constexpr int NT = K / 64;
    __shared__ bf16_t As[128 * 64];   // 16 KB
    __shared__ bf16_t Bs[192 * 64];   // 24 KB
    const int tid = threadIdx.x;
    const int wv = tid >> 6, ln = tid & 63;
    const int lrow = ln & 15, lkg = ln >> 4;
    const int r7 = lrow & 7;
    const int wm = (wv >> 1) * 64, wn = (wv & 1) * 96;
    const long m0 = (long)blockIdx.x * 128;
    const int n0 = blockIdx.y * 192;

    f32x4 acc[4][6];
    #pragma unroll
    for (int mi = 0; mi < 4; ++mi)
        #pragma unroll
        for (int ni = 0; ni < 6; ++ni)
            #pragma unroll
            for (int rg = 0; rg < 4; ++rg) acc[mi][ni][rg] = 0.f;

    for (int t = 0; t < NT; ++t) {
        // stage A tile [128][64]: 4 x 1KB per wave
        #pragma unroll
        for (int i = 0; i < 4; ++i) {
            const int off = ((wv * 4 + i) << 10) + ln * 16;
            const int row = off >> 7;
            const int c16 = ((off >> 4) & 7) ^ (row & 7);
            gl16(A + (m0 + row) * K + t * 64 + (c16 << 3),
                 (char*)As + ((wv * 4 + i) << 10));
        }
        // stage B tile [192][64]: 6 x 1KB per wave
        #pragma unroll
        for (int i = 0; i < 6; ++i) {
            const int off = ((wv * 6 + i) << 10) + ln * 16;
            const int row = off >> 7;
            const int c16 = ((off >> 4) & 7) ^ (row & 7);
            gl16(W + (long)(n0 + row) * K + t * 64 + (c16 << 3),
                 (char*)Bs + ((wv * 6 + i) << 10));
        }
        __syncthreads();
        #pragma unroll
        for (int kk = 0; kk < 2; ++kk) {
            const int kb = (((kk << 2) | lkg) ^ r7) << 4;
            bf16x8 af[4], bfr[6];
            #pragma unroll
            for (int mi = 0; mi < 4; ++mi)
                af[mi] = *(const bf16x8*)((const char*)As
                           + (wm + mi * 16 + lrow) * 128 + kb);
            #pragma unroll
            for (int ni = 0; ni < 6; ++ni)
                bfr[ni] = *(const bf16x8*)((const char*)Bs
                           + (wn + ni * 16 + lrow) * 128 + kb);
            #pragma unroll
            for (int mi = 0; mi < 4; ++mi)
                #pragma unroll
                for (int ni = 0; ni < 6; ++ni)
                    acc[mi][ni] = MFMA16(bfr[ni], af[mi], acc[mi][ni]); // swapped
        }
        __syncthreads();
    }

    // epilogue: m = ..+lrow, n = ..+lkg*4+rg -> 8B stores
    #pragma unroll
    for (int mi = 0; mi < 4; ++mi) {
        const long m = m0 + wm + mi * 16 + lrow;
        #pragma unroll
        for (int ni = 0; ni < 6; ++ni) {
            const int nb = n0 + wn + ni * 16 + lkg * 4;
            const float4 bv = *(const float4*)(bias + nb);
            float v[4] = { acc[mi][ni][0] + bv.x, acc[mi][ni][1] + bv.y,
                           acc[mi][ni][2] + bv.z, acc[mi][ni][3] + bv.w };
            bf16x4 o;
            #pragma unroll
            for (int rg = 0; rg < 4; ++rg) {
                float u = v[rg];
                if (EPI == 2) u = gelu_t(u);
                o[rg] = (bf16_t)u;
            }
            *(bf16x4*)(outp + m * N + nb) = o;
        }
    }
}

// ---------------- GEMM 128x64 (single-buffer) — used for fc2 (K=768) -----
template<int EPI, int N, int K>
__global__ __launch_bounds__(256) void k_gemm(const bf16_t* __restrict__ A,
                                              const bf16_t* __restrict__ W,
                                              const float* __restrict__ bias,
                                              bf16_t* __restrict__ outp)
{
    __shared__ bf16_t As[128 * 64];
    __shared__ bf16_t Bs[64 * 64];
    const int tid = threadIdx.x;
    const int wv = tid >> 6, ln = tid & 63;
    const int lrow = ln & 15, lkg = ln >> 4;
    const int r7 = lrow & 7;
    const int wm = (wv >> 1) * 64, wn = (wv & 1) * 32;
    const long m0 = (long)blockIdx.x * 128;
    const int n0 = blockIdx.y * 64;

    f32x4 acc[4][2];
    #pragma unroll
    for (int mi = 0; mi < 4; ++mi)
        #pragma unroll
        for (int ni = 0; ni < 2; ++ni)
            #pragma unroll
            for (int rg = 0; rg < 4; ++rg) acc[mi][ni][rg] = 0.f;

    for (int t = 0; t < K / 64; ++t) {
        #pragma unroll
        for (int i = 0; i < 4; ++i) {
            const int off = ((wv * 4 + i) << 10) + ln * 16;
            const int row = off >> 7;
            const int c16 = ((off >> 4) & 7) ^ (row & 7);
            gl16(A + (m0 + row) * K + t * 64 + (c16 << 3),
                 (char*)As + ((wv * 4 + i) << 10));
        }
        #pragma unroll
        for (int i = 0; i < 2; ++i) {
            const int off = ((wv * 2 + i) << 10) + ln * 16;
            const int row = off >> 7;
            const int c16 = ((off >> 4) & 7) ^ (row & 7);
            gl16(W + (long)(n0 + row) * K + t * 64 + (c16 << 3),
                 (char*)Bs + ((wv * 2 + i) << 10));
        }
        __syncthreads();
        #pragma unroll
        for (int kk = 0; kk < 2; ++kk) {
            const int kb = (((kk << 2) | lkg) ^ r7) << 4;
            bf16x8 af[4], bfr[2];
            #pragma unroll
            for (int mi = 0; mi < 4; ++mi)
                af[mi] = *(const bf16x8*)((const char*)As
                           + (wm + mi * 16 + lrow) * 128 + kb);
            #pragma unroll
            for (int ni = 0; ni < 2; ++ni)
                bfr[ni] = *(const bf16x8*)((const char*)Bs
                           + (wn + ni * 16 + lrow) * 128 + kb);
            #pragma unroll
            for (int mi = 0; mi < 4; ++mi)
                #pragma unroll
                for (int ni = 0; ni < 2; ++ni)
                    acc[mi][ni] = MFMA16(bfr[ni], af[mi], acc[mi][ni]); // swapped
        }
        __syncthreads();
    }

    #pragma unroll
    for (int mi = 0; mi < 4; ++mi) {
        const long m = m0 + wm + mi * 16 + lrow;
        #pragma unroll
        for (int ni = 0; ni < 2; ++ni) {
            const int nb = n0 + wn + ni * 16 + lkg * 4;
            const float4 bv = *(const float4*)(bias + nb);
            float v[4] = { acc[mi][ni][0] + bv.x, acc[mi][ni][1] + bv.y,
                           acc[mi][ni][2] + bv.z, acc[mi][ni][3] + bv.w };
            bf16x4 o;
            #pragma unroll
            for (int rg = 0; rg < 4; ++rg) {
                float u = v[rg];
                if (EPI == 2) u = gelu_t(u);
                o[rg] = (bf16_t)u;
            }
            *(bf16x4*)(outp + m * N + nb) = o;
        }
    }
}

// ------- proj GEMM (N=192, K=192) with fused LN2 epilogue -> bf16 --------
__global__ __launch_bounds__(256) void k_proj_ln(const bf16_t* __restrict__ A,
                                                 const bf16_t* __restrict__ W,
                                                 const float* __restrict__ bias,
                                                 const float* __restrict__ gam,
                                                 const float* __restrict__ bet,
                                                 bf16_t* __restrict__ out)
{
    __shared__ bf16_t As[128][72];   // 18 KB
    __shared__ bf16_t Bs[192][72];   // 27 KB
    const int tid = threadIdx.x;
    const int wave = tid >> 6, lane = tid & 63;
    const int lrow = lane & 15, lkg = lane >> 4;
    const int wm = wave * 32;
    const long m0 = (long)blockIdx.x * 128;

    f32x4 acc[2][12];
    #pragma unroll
    for (int mi = 0; mi < 2; ++mi)
        #pragma unroll
        for (int ni = 0; ni < 12; ++ni)
            #pragma unroll
            for (int rg = 0; rg < 4; ++rg) acc[mi][ni][rg] = 0.f;

    for (int k0 = 0; k0 < 192; k0 += 64) {
        #pragma unroll
        for (int it = 0; it < 4; ++it) {
            int e = (tid + it * 256) * 8;
            int r = e >> 6, c = e & 63;
            *(int4*)(&As[r][c]) = *(const int4*)(A + (m0 + r) * 192 + (k0 + c));
        }
        #pragma unroll
        for (int it = 0; it < 6; ++it) {
            int e = (tid + it * 256) * 8;
            int r = e >> 6, c = e & 63;
            *(int4*)(&Bs[r][c]) = *(const int4*)(W + (long)r * 192 + (k0 + c));
        }
        __syncthreads();
        #pragma unroll
        for (int kk = 0; kk < 64; kk += 32) {
            bf16x8 af[2];
            #pragma unroll
            for (int mi = 0; mi < 2; ++mi)
                af[mi] = *(const bf16x8*)(&As[wm + mi * 16 + lrow][kk + lkg * 8]);
            #pragma unroll
            for (int ni = 0; ni < 12; ++ni) {
                bf16x8 bfr = *(const bf16x8*)(&Bs[ni * 16 + lrow][kk + lkg * 8]);
                acc[0][ni] = MFMA16(af[0], bfr, acc[0][ni]);
                acc[1][ni] = MFMA16(af[1], bfr, acc[1][ni]);
            }
        }
        __syncthreads();
    }

    float bv[12];
    #pragma unroll
    for (int ni = 0; ni < 12; ++ni) bv[ni] = bias[ni * 16 + lrow];

    #pragma unroll
    for (int mi = 0; mi < 2; ++mi) {
        #pragma unroll
        for (int rg = 0; rg < 4; ++rg) {
            float val[12];
            float s = 0.f, sq = 0.f;
            #pragma unroll
            for (int ni = 0; ni < 12; ++ni) {
                val[ni] = acc[mi][ni][rg] + bv[ni];
                s += val[ni];
                sq += val[ni] * val[ni];
            }
            #pragma unroll
            for (int d = 1; d < 16; d <<= 1) {
                s += __shfl_xor(s, d);
                sq += __shfl_xor(sq, d);
            }
            float mean = s * (1.f / 192.f);
            float var  = sq * (1.f / 192.f) - mean * mean;
            float rs = rsqrtf(var + 1e-5f);
            const long row = m0 + wm + mi * 16 + lkg * 4 + rg;
            bf16_t* orow = out + row * 192;
            #pragma unroll
            for (int ni = 0; ni < 12; ++ni) {
                const int col = ni * 16 + lrow;
                orow[col] = (bf16_t)((val[ni] - mean) * rs * gam[col] + bet[col]);
            }
        }
    }
}

// ---------------- window attention: 1 wave per (window, head) ------------
__global__ __launch_bounds__(64) void k_attn(const bf16_t* __restrict__ qkv,
                                             bf16_t* __restrict__ aout)
{
    __shared__ bf16_t Pl[64][72];
    __shared__ bf16_t Vt[32][72];   // V transposed: Vt[d][m]
    const int win = blockIdx.x, head = blockIdx.y;
    const int lane = threadIdx.x;
    const int lrow = lane & 15, lkg = lane >> 4;
    const bf16_t* base = qkv + (long)win * 28224 + head * 32;  // 49*576

    // stage V^T into LDS (rows m>=49 zeroed)
    {
        const int m = lane;
        const int mc = (m < 49) ? m : 48;
        const int4* vr = (const int4*)(base + (long)mc * 576 + 384);
        #pragma unroll
        for (int c4 = 0; c4 < 4; ++c4) {
            int4 vv = vr[c4];
            if (m >= 49) vv = make_int4(0, 0, 0, 0);
            const bf16_t* pe = (const bf16_t*)&vv;
            #pragma unroll
            for (int e = 0; e < 8; ++e) Vt[c4 * 8 + e][m] = pe[e];
        }
    }

    // QK^T: S[n][m] = sum_d q[n][d] k[m][d], padded 49->64
    bf16x8 z8;
    #pragma unroll
    for (int e = 0; e < 8; ++e) z8[e] = (bf16_t)0.f;
    bf16x8 qf[4], kf[4];
    #pragma unroll
    for (int t = 0; t < 4; ++t) {
        const int n = t * 16 + lrow;
        const int nc = (n < 49) ? n : 48;
        bf16x8 qv = *(const bf16x8*)(base + (long)nc * 576 + lkg * 8);
        bf16x8 kv = *(const bf16x8*)(base + (long)nc * 576 + 192 + lkg * 8);
        qf[t] = (n < 49) ? qv : z8;
        kf[t] = (n < 49) ? kv : z8;
    }
    f32x4 zf; zf[0] = zf[1] = zf[2] = zf[3] = 0.f;
    f32x4 S[4][4];
    #pragma unroll
    for (int mi = 0; mi < 4; ++mi)
        #pragma unroll
        for (int mj = 0; mj < 4; ++mj)
            S[mi][mj] = MFMA16(qf[mi], kf[mj], zf);

    // row softmax (cols >= 49 masked), P -> LDS as bf16
    const float scl = 0.17677669529663687f;   // 32^-0.5
    #pragma unroll
    for (int mi = 0; mi < 4; ++mi) {
        #pragma unroll
        for (int rg = 0; rg < 4; ++rg) {
            float v0 = S[mi][0][rg] * scl;
            float v1 = S[mi][1][rg] * scl;
            float v2 = S[mi][2][rg] * scl;
            float v3 = (lrow == 0) ? S[mi][3][rg] * scl : -1e30f;  // col 48+lrow
            float mx = fmaxf(fmaxf(v0, v1), fmaxf(v2, v3));
            #pragma unroll
            for (int d = 1; d < 16; d <<= 1) mx = fmaxf(mx, __shfl_xor(mx, d));
            float e0 = expf(v0 - mx), e1 = expf(v1 - mx), e2 = expf(v2 - mx);
            float e3 = (lrow == 0) ? expf(v3 - mx) : 0.f;
            float sm = e0 + e1 + e2 + e3;
            #pragma unroll
            for (int d = 1; d < 16; d <<= 1) sm += __shfl_xor(sm, d);
            float is = 1.f / sm;
            const int row = mi * 16 + lkg * 4 + rg;
            Pl[row][lrow]      = (bf16_t)(e0 * is);
            Pl[row][16 + lrow] = (bf16_t)(e1 * is);
            Pl[row][32 + lrow] = (bf16_t)(e2 * is);
            Pl[row][48 + lrow] = (bf16_t)(e3 * is);
        }
    }
    __syncthreads();

    // PV: out[n][d] = sum_m P[n][m] Vt[d][m]
    f32x4 o[4][2];
    #pragma unroll
    for (int ni = 0; ni < 4; ++ni)
        #pragma unroll
        for (int di = 0; di < 2; ++di)
            #pragma unroll
            for (int rg = 0; rg < 4; ++rg) o[ni][di][rg] = 0.f;
    #pragma unroll
    for (int m0 = 0; m0 < 64; m0 += 32) {
        bf16x8 pf[4], vf[2];
        #pragma unroll
        for (int ni = 0; ni < 4; ++ni)
            pf[ni] = *(const bf16x8*)(&Pl[ni * 16 + lrow][m0 + lkg * 8]);
        #pragma unroll
        for (int di = 0; di < 2; ++di)
            vf[di] = *(const bf16x8*)(&Vt[di * 16 + lrow][m0 + lkg * 8]);
        #pragma unroll
        for (int ni = 0; ni < 4; ++ni)
            #pragma unroll
            for (int di = 0; di < 2; ++di)
                o[ni][di] = MFMA16(pf[ni], vf[di], o[ni][di]);
    }
    #pragma unroll
    for (int ni = 0; ni < 4; ++ni) {
        #pragma unroll
        for (int rg = 0; rg < 4; ++rg) {
            const int n = ni * 16 + lkg * 4 + rg;
            if (n < 49) {
                bf16_t* orow = aout + ((long)win * 49 + n) * 192 + head * 32;
                orow[lrow]      = (bf16_t)o[ni][0][rg];
                orow[16 + lrow] = (bf16_t)o[ni][1][rg];
            }
        }
    }
}

// ---------------- final: un-window + roll(+3) + BHWC->BCHW + shortcut ----
__global__ __launch_bounds__(1024) void k_final(const bf16_t* __restrict__ fb,
                                                const float* __restrict__ x,
                                                float* __restrict__ out)
{
    __shared__ float tile[56][199];   // odd-ish stride: conflict-free col reads
    const int bh = blockIdx.x;
    const int b = bh / 56, hq = bh % 56;
    const int tid = threadIdx.x;
    const int hr = (hq + 53) % 56;
    const int nh = hr / 7, ii = hr % 7;
    const long rband = ((long)b * 64 + (long)nh * 8) * 49 + (long)ii * 7;

    // phase 1: gather fb rows (contiguous 384B/row) into tile[wq][c]
    for (int q = tid; q < 1344; q += 1024) {
        const int g = q / 168, rem = q % 168;
        const int jj = rem / 24, ci = rem % 24;
        const long rr = rband + (long)g * 49 + jj;
        bf16x8 v = *(const bf16x8*)(fb + rr * 192 + ci * 8);
        const int wq = (g * 7 + jj + 3) % 56;
        #pragma unroll
        for (int e = 0; e < 8; ++e) tile[wq][ci * 8 + e] = (float)v[e];
    }
    __syncthreads();

    // phase 2: out[b][c][hq][w] = tile[w][c] + x[b][c][hq][w]  (float4 along w)
    const int g = tid >> 4, u = tid & 15;
    if (u < 14) {
        #pragma unroll
        for (int k = 0; k < 3; ++k) {
            const int c = g + 64 * k;
            const long base = ((long)b * 192 + c) * 3136 + (long)hq * 56 + u * 4;
            float4 xv = *(const float4*)(x + base);
            float4 ov;
            ov.x = tile[u * 4 + 0][c] + xv.x;
            ov.y = tile[u * 4 + 1][c] + xv.y;
            ov.z = tile[u * 4 + 2][c] + xv.z;
            ov.w = tile[u * 4 + 3][c] + xv.w;
            *(float4*)(out + base) = ov;
        }
    }
}

extern "C" void kernel_launch(void* const* d_in, const int* in_sizes, int n_in,
                              void* d_out, int out_size, void* d_ws, size_t ws_size,
                              hipStream_t stream)
{
    const float* x     = (const float*)d_in[0];
    const float* n1w   = (const float*)d_in[1];
    const float* n1b   = (const float*)d_in[2];
    const float* qkvw  = (const float*)d_in[3];
    const float* qkvb  = (const float*)d_in[4];
    const float* projw = (const float*)d_in[5];
    const float* projb = (const float*)d_in[6];
    const float* n2w   = (const float*)d_in[7];
    const float* n2b   = (const float*)d_in[8];
    const float* fc1w  = (const float*)d_in[9];
    const float* fc1b  = (const float*)d_in[10];
    const float* fc2w  = (const float*)d_in[11];
    const float* fc2b  = (const float*)d_in[12];

    char* ws = (char*)d_ws;
    bf16_t* wqkv  = (bf16_t*)(ws);              // 576*192  bf16
    bf16_t* wproj = (bf16_t*)(ws + 221184);     // 192*192
    bf16_t* wfc1  = (bf16_t*)(ws + 294912);     // 768*192
    bf16_t* wfc2  = (bf16_t*)(ws + 589824);     // 192*768
    bf16_t* Xb    = (bf16_t*)(ws + 884736);     // [50176][192] bf16 (LN1 out, attn out)
    bf16_t* QKV   = (bf16_t*)(ws + 20152320);   // [50176][576] bf16
    bf16_t* Hb    = (bf16_t*)(ws + 77955072);   // [50176][768] bf16 (fc1 out)
    bf16_t* H2    = (bf16_t*)(ws + 155025408);  // [50176][192] bf16 (fc2 out)
    bf16_t* X2    = (bf16_t*)(ws + 174292992);  // [50176][192] bf16 (LN2 out)

    k_cvt<<<1728, 256, 0, stream>>>(qkvw, projw, fc1w, fc2w, wqkv);
    k_ln1<<<896, 1024, 0, stream>>>(x, n1w, n1b, Xb);
    k_gemm192<0, 576, 192><<<dim3(392, 3), 256, 0, stream>>>(Xb, wqkv, qkvb, QKV);
    k_attn<<<dim3(1024, 6), 64, 0, stream>>>(QKV, Xb);
    k_proj_ln<<<392, 256, 0, stream>>>(Xb, wproj, projb, n2w, n2b, X2);
    k_gemm192<2, 768, 192><<<dim3(392, 4), 256, 0, stream>>>(X2, wfc1, fc1b, Hb);
    k_gemm<0, 192, 768><<<dim3(392, 3), 256, 0, stream>>>(Hb, wfc2, fc2b, H2);
    k_final<<<896, 1024, 0, stream>>>(H2, x, (float*)d_out);
}

// Round 9
// 210.068 us; speedup vs baseline: 1.2154x; 1.1655x over previous
//
#include <hip/hip_runtime.h>
#include <hip/hip_bf16.h>

typedef __bf16 bf16_t;
typedef __bf16 bf16x4 __attribute__((ext_vector_type(4)));
typedef __bf16 bf16x8 __attribute__((ext_vector_type(8)));
typedef float f32x4 __attribute__((ext_vector_type(4)));

#define MFMA16(a, b, c) __builtin_amdgcn_mfma_f32_16x16x32_bf16((a), (b), (c), 0, 0, 0)

// async global->LDS, 16B per lane; dest = wave-uniform base + lane*16
__device__ __forceinline__ void gl16(const bf16_t* g, void* l) {
    __builtin_amdgcn_global_load_lds(
        (const __attribute__((address_space(1))) void*)g,
        (__attribute__((address_space(3))) void*)l, 16, 0, 0);
}

__device__ __forceinline__ float gelu_t(float u) {
    float t2 = fminf(u * (1.5957691216057308f + 0.07135481627f * u * u), 60.f);
    float e = __expf(t2);
    return u * e / (e + 1.f);
}

// Problem constants
// B=16, C=192, H=W=56, WIN=7, SHIFT=3, HEADS=6, DH=32, HID=768
// tokens M = 16*8*8*49 = 50176, windows = 1024

// ---------------- weight convert (4 weights -> contiguous bf16) ----------
__global__ __launch_bounds__(256) void k_cvt(const float* __restrict__ qkvw,
                                             const float* __restrict__ projw,
                                             const float* __restrict__ fc1w,
                                             const float* __restrict__ fc2w,
                                             bf16_t* __restrict__ dst)
{
    int i = blockIdx.x * 256 + threadIdx.x;
    if (i >= 442368) return;
    float v;
    if (i < 110592)      v = qkvw[i];
    else if (i < 147456) v = projw[i - 110592];
    else if (i < 294912) v = fc1w[i - 147456];
    else                 v = fc2w[i - 294912];
    dst[i] = (bf16_t)v;
}

// ---------------- LN1 + roll(-3) + window partition -> xw bf16 -----------
__global__ __launch_bounds__(1024) void k_ln1(const float* __restrict__ x,
                                              const float* __restrict__ gam,
                                              const float* __restrict__ bet,
                                              bf16_t* __restrict__ xw)
{
    __shared__ float tile[56][193];     // odd stride: conflict-free row reads
    __shared__ bf16_t obuf[56 * 192];   // row stride 384B = 24 int4
    const int bh = blockIdx.x;
    const int b = bh / 56, h = bh % 56;
    const int tid = threadIdx.x;

    // phase 1: x[b][:][h][:] -> tile[w][c] (float4 global loads)
    {
        const int g = tid >> 4, u = tid & 15;   // g: channel group 0..63
        const float* xb = x + (long)b * 602112 + (long)h * 56;
        if (u < 14) {
            #pragma unroll
            for (int k = 0; k < 3; ++k) {
                const int c = g + 64 * k;
                float4 v = *(const float4*)(xb + (long)c * 3136 + u * 4);
                tile[u * 4 + 0][c] = v.x;
                tile[u * 4 + 1][c] = v.y;
                tile[u * 4 + 2][c] = v.z;
                tile[u * 4 + 3][c] = v.w;
            }
        }
    }
    __syncthreads();

    // phase 2: LN per token (wave-parallel over w), bf16 -> obuf by rolled idx
    const int wave = tid >> 6, lane = tid & 63;
    const float g0 = gam[lane], g1 = gam[lane + 64], g2 = gam[lane + 128];
    const float b0 = bet[lane], b1 = bet[lane + 64], b2 = bet[lane + 128];
    for (int wp = wave; wp < 56; wp += 16) {
        float v0 = tile[wp][lane], v1 = tile[wp][lane + 64], v2 = tile[wp][lane + 128];
        float s = v0 + v1 + v2;
        float sq = v0 * v0 + v1 * v1 + v2 * v2;
        #pragma unroll
        for (int d = 1; d < 64; d <<= 1) { s += __shfl_xor(s, d); sq += __shfl_xor(sq, d); }
        float mean = s * (1.f / 192.f);
        float var  = sq * (1.f / 192.f) - mean * mean;
        float rs = rsqrtf(var + 1e-5f);
        const int wr = (wp + 53) % 56;
        bf16_t* o = obuf + wr * 192;
        o[lane]       = (bf16_t)((v0 - mean) * rs * g0 + b0);
        o[lane + 64]  = (bf16_t)((v1 - mean) * rs * g1 + b1);
        o[lane + 128] = (bf16_t)((v2 - mean) * rs * g2 + b2);
    }
    __syncthreads();

    // phase 3: obuf -> xw, 8 window-groups x 7 contiguous rows (int4 stores)
    const int hr = (h + 53) % 56;
    const int nh = hr / 7, ii = hr % 7;
    const long rband = ((long)b * 64 + (long)nh * 8) * 49 + (long)ii * 7;
    const int4* src = (const int4*)obuf;
    for (int q = tid; q < 1344; q += 1024) {
        const int g = q / 168, u = q % 168;
        const int jj = u / 24, ci = u % 24;
        const long r = rband + (long)g * 49 + jj;
        ((int4*)xw)[r * 24 + ci] = src[(g * 7 + jj) * 24 + ci];
    }
}

// ---- one-shot GEMM for K=192: stage full A/B panels, ONE barrier --------
// Block 64m x 64n, 4 waves (2m x 2n), wave tile 32x32.
// LDS rows are 384B = 24 x 16B slots; slot low-3-bits XOR row&7 (pre-swizzled
// source + swizzled read) -> 2-way banks (free). No K-loop, no re-staging.
// EPI: 0 = bf16 out, 2 = bf16 out + tanh-GELU
template<int EPI, int N>
__global__ __launch_bounds__(256) void k_gemm_1s(const bf16_t* __restrict__ A,
                                                 const bf16_t* __restrict__ W,
                                                 const float* __restrict__ bias,
                                                 bf16_t* __restrict__ outp)
{
    __shared__ bf16_t As[64 * 192];   // 24 KB
    __shared__ bf16_t Bs[64 * 192];   // 24 KB
    const int tid = threadIdx.x;
    const int wv = tid >> 6, ln = tid & 63;
    const int lrow = ln & 15, lkg = ln >> 4;
    const int r7 = lrow & 7;
    const int wm = (wv >> 1) * 32, wn = (wv & 1) * 32;
    const long m0 = (long)blockIdx.x * 64;
    const int n0 = blockIdx.y * 64;

    // stage A[64][192] + B[64][192]: 6+6 x 1KB per wave, sources pre-swizzled
    #pragma unroll
    for (int i = 0; i < 6; ++i) {
        const int off = ((wv * 6 + i) << 10) + ln * 16;
        const int row = off / 384;
        const int slot = (off % 384) >> 4;
        const int col = ((slot & 24) | ((slot & 7) ^ (row & 7))) << 3;
        gl16(A + (m0 + row) * 192 + col, (char*)As + ((wv * 6 + i) << 10));
    }
    #pragma unroll
    for (int i = 0; i < 6; ++i) {
        const int off = ((wv * 6 + i) << 10) + ln * 16;
        const int row = off / 384;
        const int slot = (off % 384) >> 4;
        const int col = ((slot & 24) | ((slot & 7) ^ (row & 7))) << 3;
        gl16(W + (long)(n0 + row) * 192 + col, (char*)Bs + ((wv * 6 + i) << 10));
    }
    __syncthreads();   // the ONLY barrier: drains the 12 DMA issues

    f32x4 acc[2][2];
    #pragma unroll
    for (int mi = 0; mi < 2; ++mi)
        #pragma unroll
        for (int ni = 0; ni < 2; ++ni)
            #pragma unroll
            for (int rg = 0; rg < 4; ++rg) acc[mi][ni][rg] = 0.f;

    #pragma unroll
    for (int kk = 0; kk < 6; ++kk) {
        const int s = kk * 4 + lkg;                       // logical slot 0..23
        const int kb = ((s & 24) | ((s & 7) ^ r7)) << 4;  // swizzled byte
        bf16x8 af[2], bfr[2];
        #pragma unroll
        for (int mi = 0; mi < 2; ++mi)
            af[mi] = *(const bf16x8*)((const char*)As
                       + (wm + mi * 16 + lrow) * 384 + kb);
        #pragma unroll
        for (int ni = 0; ni < 2; ++ni)
            bfr[ni] = *(const bf16x8*)((const char*)Bs
                       + (wn + ni * 16 + lrow) * 384 + kb);
        #pragma unroll
        for (int mi = 0; mi < 2; ++mi)
            #pragma unroll
            for (int ni = 0; ni < 2; ++ni)
                acc[mi][ni] = MFMA16(bfr[ni], af[mi], acc[mi][ni]);  // swapped
    }

    // epilogue: m = ..+lrow, n = ..+lkg*4+rg -> 8B stores (64B/row/block)
    #pragma unroll
    for (int mi = 0; mi < 2; ++mi) {
        const long m = m0 + wm + mi * 16 + lrow;
        #pragma unroll
        for (int ni = 0; ni < 2; ++ni) {
            const int nb = n0 + wn + ni * 16 + lkg * 4;
            const float4 bv = *(const float4*)(bias + nb);
            float v[4] = { acc[mi][ni][0] + bv.x, acc[mi][ni][1] + bv.y,
                           acc[mi][ni][2] + bv.z, acc[mi][ni][3] + bv.w };
            bf16x4 o;
            #pragma unroll
            for (int rg = 0; rg < 4; ++rg) {
                float u = v[rg];
                if (EPI == 2) u = gelu_t(u);
                o[rg] = (bf16_t)u;
            }
            *(bf16x4*)(outp + m * N + nb) = o;
        }
    }
}

// ---------------- GEMM 128x64 (single-buffer) — used for fc2 (K=768) -----
template<int EPI, int N, int K>
__global__ __launch_bounds__(256) void k_gemm(const bf16_t* __restrict__ A,
                                              const bf16_t* __restrict__ W,
                                              const float* __restrict__ bias,
                                              bf16_t* __restrict__ outp)
{
    __shared__ bf16_t As[128 * 64];
    __shared__ bf16_t Bs[64 * 64];
    const int tid = threadIdx.x;
    const int wv = tid >> 6, ln = tid & 63;
    const int lrow = ln & 15, lkg = ln >> 4;
    const int r7 = lrow & 7;
    const int wm = (wv >> 1) * 64, wn = (wv & 1) * 32;
    const long m0 = (long)blockIdx.x * 128;
    const int n0 = blockIdx.y * 64;

    f32x4 acc[4][2];
    #pragma unroll
    for (int mi = 0; mi < 4; ++mi)
        #pragma unroll
        for (int ni = 0; ni < 2; ++ni)
            #pragma unroll
            for (int rg = 0; rg < 4; ++rg) acc[mi][ni][rg] = 0.f;

    for (int t = 0; t < K / 64; ++t) {
        #pragma unroll
        for (int i = 0; i < 4; ++i) {
            const int off = ((wv * 4 + i) << 10) + ln * 16;
            const int row = off >> 7;
            const int c16 = ((off >> 4) & 7) ^ (row & 7);
            gl16(A + (m0 + row) * K + t * 64 + (c16 << 3),
                 (char*)As + ((wv * 4 + i) << 10));
        }
        #pragma unroll
        for (int i = 0; i < 2; ++i) {
            const int off = ((wv * 2 + i) << 10) + ln * 16;
            const int row = off >> 7;
            const int c16 = ((off >> 4) & 7) ^ (row & 7);
            gl16(W + (long)(n0 + row) * K + t * 64 + (c16 << 3),
                 (char*)Bs + ((wv * 2 + i) << 10));
        }
        __syncthreads();
        #pragma unroll
        for (int kk = 0; kk < 2; ++kk) {
            const int kb = (((kk << 2) | lkg) ^ r7) << 4;
            bf16x8 af[4], bfr[2];
            #pragma unroll
            for (int mi = 0; mi < 4; ++mi)
                af[mi] = *(const bf16x8*)((const char*)As
                           + (wm + mi * 16 + lrow) * 128 + kb);
            #pragma unroll
            for (int ni = 0; ni < 2; ++ni)
                bfr[ni] = *(const bf16x8*)((const char*)Bs
                           + (wn + ni * 16 + lrow) * 128 + kb);
            #pragma unroll
            for (int mi = 0; mi < 4; ++mi)
                #pragma unroll
                for (int ni = 0; ni < 2; ++ni)
                    acc[mi][ni] = MFMA16(bfr[ni], af[mi], acc[mi][ni]); // swapped
        }
        __syncthreads();
    }

    #pragma unroll
    for (int mi = 0; mi < 4; ++mi) {
        const long m = m0 + wm + mi * 16 + lrow;
        #pragma unroll
        for (int ni = 0; ni < 2; ++ni) {
            const int nb = n0 + wn + ni * 16 + lkg * 4;
            const float4 bv = *(const float4*)(bias + nb);
            float v[4] = { acc[mi][ni][0] + bv.x, acc[mi][ni][1] + bv.y,
                           acc[mi][ni][2] + bv.z, acc[mi][ni][3] + bv.w };
            bf16x4 o;
            #pragma unroll
            for (int rg = 0; rg < 4; ++rg) {
                float u = v[rg];
                if (EPI == 2) u = gelu_t(u);
                o[rg] = (bf16_t)u;
            }
            *(bf16x4*)(outp + m * N + nb) = o;
        }
    }
}

// ------- proj GEMM (N=192, K=192) + fused LN2, 64-row blocks -------------
__global__ __launch_bounds__(256) void k_proj_ln(const bf16_t* __restrict__ A,
                                                 const bf16_t* __restrict__ W,
                                                 const float* __restrict__ bias,
                                                 const float* __restrict__ gam,
                                                 const float* __restrict__ bet,
                                                 bf16_t* __restrict__ out)
{
    __shared__ bf16_t As[64][72];    // 9 KB
    __shared__ bf16_t Bs[192][72];   // 27 KB
    const int tid = threadIdx.x;
    const int wave = tid >> 6, lane = tid & 63;
    const int lrow = lane & 15, lkg = lane >> 4;
    const int wm = wave * 16;
    const long m0 = (long)blockIdx.x * 64;

    f32x4 acc[12];
    #pragma unroll
    for (int ni = 0; ni < 12; ++ni)
        #pragma unroll
        for (int rg = 0; rg < 4; ++rg) acc[ni][rg] = 0.f;

    for (int k0 = 0; k0 < 192; k0 += 64) {
        #pragma unroll
        for (int it = 0; it < 2; ++it) {
            int e = (tid + it * 256) * 8;
            int r = e >> 6, c = e & 63;
            *(int4*)(&As[r][c]) = *(const int4*)(A + (m0 + r) * 192 + (k0 + c));
        }
        #pragma unroll
        for (int it = 0; it < 6; ++it) {
            int e = (tid + it * 256) * 8;
            int r = e >> 6, c = e & 63;
            *(int4*)(&Bs[r][c]) = *(const int4*)(W + (long)r * 192 + (k0 + c));
        }
        __syncthreads();
        #pragma unroll
        for (int kk = 0; kk < 64; kk += 32) {
            bf16x8 af = *(const bf16x8*)(&As[wm + lrow][kk + lkg * 8]);
            #pragma unroll
            for (int ni = 0; ni < 12; ++ni) {
                bf16x8 bfr = *(const bf16x8*)(&Bs[ni * 16 + lrow][kk + lkg * 8]);
                acc[ni] = MFMA16(af, bfr, acc[ni]);
            }
        }
        __syncthreads();
    }

    float bv[12];
    #pragma unroll
    for (int ni = 0; ni < 12; ++ni) bv[ni] = bias[ni * 16 + lrow];

    #pragma unroll
    for (int rg = 0; rg < 4; ++rg) {
        float val[12];
        float s = 0.f, sq = 0.f;
        #pragma unroll
        for (int ni = 0; ni < 12; ++ni) {
            val[ni] = acc[ni][rg] + bv[ni];
            s += val[ni];
            sq += val[ni] * val[ni];
        }
        #pragma unroll
        for (int d = 1; d < 16; d <<= 1) {
            s += __shfl_xor(s, d);
            sq += __shfl_xor(sq, d);
        }
        float mean = s * (1.f / 192.f);
        float var  = sq * (1.f / 192.f) - mean * mean;
        float rs = rsqrtf(var + 1e-5f);
        const long row = m0 + wm + lkg * 4 + rg;
        bf16_t* orow = out + row * 192;
        #pragma unroll
        for (int ni = 0; ni < 12; ++ni) {
            const int col = ni * 16 + lrow;
            orow[col] = (bf16_t)((val[ni] - mean) * rs * gam[col] + bet[col]);
        }
    }
}

// ---------------- window attention: 1 wave per (window, head) ------------
__global__ __launch_bounds__(64) void k_attn(const bf16_t* __restrict__ qkv,
                                             bf16_t* __restrict__ aout)
{
    __shared__ bf16_t Pl[64][72];
    __shared__ bf16_t Vt[32][72];   // V transposed: Vt[d][m]
    const int win = blockIdx.x, head = blockIdx.y;
    const int lane = threadIdx.x;
    const int lrow = lane & 15, lkg = lane >> 4;
    const bf16_t* base = qkv + (long)win * 28224 + head * 32;  // 49*576

    // stage V^T into LDS (rows m>=49 zeroed)
    {
        const int m = lane;
        const int mc = (m < 49) ? m : 48;
        const int4* vr = (const int4*)(base + (long)mc * 576 + 384);
        #pragma unroll
        for (int c4 = 0; c4 < 4; ++c4) {
            int4 vv = vr[c4];
            if (m >= 49) vv = make_int4(0, 0, 0, 0);
            const bf16_t* pe = (const bf16_t*)&vv;
            #pragma unroll
            for (int e = 0; e < 8; ++e) Vt[c4 * 8 + e][m] = pe[e];
        }
    }

    // QK^T: S[n][m] = sum_d q[n][d] k[m][d], padded 49->64
    bf16x8 z8;
    #pragma unroll
    for (int e = 0; e < 8; ++e) z8[e] = (bf16_t)0.f;
    bf16x8 qf[4], kf[4];
    #pragma unroll
    for (int t = 0; t < 4; ++t) {
        const int n = t * 16 + lrow;
        const int nc = (n < 49) ? n : 48;
        bf16x8 qv = *(const bf16x8*)(base + (long)nc * 576 + lkg * 8);
        bf16x8 kv = *(const bf16x8*)(base + (long)nc * 576 + 192 + lkg * 8);
        qf[t] = (n < 49) ? qv : z8;
        kf[t] = (n < 49) ? kv : z8;
    }
    f32x4 zf; zf[0] = zf[1] = zf[2] = zf[3] = 0.f;
    f32x4 S[4][4];
    #pragma unroll
    for (int mi = 0; mi < 4; ++mi)
        #pragma unroll
        for (int mj = 0; mj < 4; ++mj)
            S[mi][mj] = MFMA16(qf[mi], kf[mj], zf);

    // row softmax (cols >= 49 masked), P -> LDS as bf16
    const float scl = 0.17677669529663687f;   // 32^-0.5
    #pragma unroll
    for (int mi = 0; mi < 4; ++mi) {
        #pragma unroll
        for (int rg = 0; rg < 4; ++rg) {
            float v0 = S[mi][0][rg] * scl;
            float v1 = S[mi][1][rg] * scl;
            float v2 = S[mi][2][rg] * scl;
            float v3 = (lrow == 0) ? S[mi][3][rg] * scl : -1e30f;  // col 48+lrow
            float mx = fmaxf(fmaxf(v0, v1), fmaxf(v2, v3));
            #pragma unroll
            for (int d = 1; d < 16; d <<= 1) mx = fmaxf(mx, __shfl_xor(mx, d));
            float e0 = expf(v0 - mx), e1 = expf(v1 - mx), e2 = expf(v2 - mx);
            float e3 = (lrow == 0) ? expf(v3 - mx) : 0.f;
            float sm = e0 + e1 + e2 + e3;
            #pragma unroll
            for (int d = 1; d < 16; d <<= 1) sm += __shfl_xor(sm, d);
            float is = 1.f / sm;
            const int row = mi * 16 + lkg * 4 + rg;
            Pl[row][lrow]      = (bf16_t)(e0 * is);
            Pl[row][16 + lrow] = (bf16_t)(e1 * is);
            Pl[row][32 + lrow] = (bf16_t)(e2 * is);
            Pl[row][48 + lrow] = (bf16_t)(e3 * is);
        }
    }
    __syncthreads();

    // PV: out[n][d] = sum_m P[n][m] Vt[d][m]
    f32x4 o[4][2];
    #pragma unroll
    for (int ni = 0; ni < 4; ++ni)
        #pragma unroll
        for (int di = 0; di < 2; ++di)
            #pragma unroll
            for (int rg = 0; rg < 4; ++rg) o[ni][di][rg] = 0.f;
    #pragma unroll
    for (int m0 = 0; m0 < 64; m0 += 32) {
        bf16x8 pf[4], vf[2];
        #pragma unroll
        for (int ni = 0; ni < 4; ++ni)
            pf[ni] = *(const bf16x8*)(&Pl[ni * 16 + lrow][m0 + lkg * 8]);
        #pragma unroll
        for (int di = 0; di < 2; ++di)
            vf[di] = *(const bf16x8*)(&Vt[di * 16 + lrow][m0 + lkg * 8]);
        #pragma unroll
        for (int ni = 0; ni < 4; ++ni)
            #pragma unroll
            for (int di = 0; di < 2; ++di)
                o[ni][di] = MFMA16(pf[ni], vf[di], o[ni][di]);
    }
    #pragma unroll
    for (int ni = 0; ni < 4; ++ni) {
        #pragma unroll
        for (int rg = 0; rg < 4; ++rg) {
            const int n = ni * 16 + lkg * 4 + rg;
            if (n < 49) {
                bf16_t* orow = aout + ((long)win * 49 + n) * 192 + head * 32;
                orow[lrow]      = (bf16_t)o[ni][0][rg];
                orow[16 + lrow] = (bf16_t)o[ni][1][rg];
            }
        }
    }
}

// ---------------- final: un-window + roll(+3) + BHWC->BCHW + shortcut ----
__global__ __launch_bounds__(1024) void k_final(const bf16_t* __restrict__ fb,
                                                const float* __restrict__ x,
                                                float* __restrict__ out)
{
    __shared__ float tile[56][199];   // odd-ish stride: conflict-free col reads
    const int bh = blockIdx.x;
    const int b = bh / 56, hq = bh % 56;
    const int tid = threadIdx.x;
    const int hr = (hq + 53) % 56;
    const int nh = hr / 7, ii = hr % 7;
    const long rband = ((long)b * 64 + (long)nh * 8) * 49 + (long)ii * 7;

    // phase 1: gather fb rows (contiguous 384B/row) into tile[wq][c]
    for (int q = tid; q < 1344; q += 1024) {
        const int g = q / 168, rem = q % 168;
        const int jj = rem / 24, ci = rem % 24;
        const long rr = rband + (long)g * 49 + jj;
        bf16x8 v = *(const bf16x8*)(fb + rr * 192 + ci * 8);
        const int wq = (g * 7 + jj + 3) % 56;
        #pragma unroll
        for (int e = 0; e < 8; ++e) tile[wq][ci * 8 + e] = (float)v[e];
    }
    __syncthreads();

    // phase 2: out[b][c][hq][w] = tile[w][c] + x[b][c][hq][w]  (float4 along w)
    const int g = tid >> 4, u = tid & 15;
    if (u < 14) {
        #pragma unroll
        for (int k = 0; k < 3; ++k) {
            const int c = g + 64 * k;
            const long base = ((long)b * 192 + c) * 3136 + (long)hq * 56 + u * 4;
            float4 xv = *(const float4*)(x + base);
            float4 ov;
            ov.x = tile[u * 4 + 0][c] + xv.x;
            ov.y = tile[u * 4 + 1][c] + xv.y;
            ov.z = tile[u * 4 + 2][c] + xv.z;
            ov.w = tile[u * 4 + 3][c] + xv.w;
            *(float4*)(out + base) = ov;
        }
    }
}

extern "C" void kernel_launch(void* const* d_in, const int* in_sizes, int n_in,
                              void* d_out, int out_size, void* d_ws, size_t ws_size,
                              hipStream_t stream)
{
    const float* x     = (const float*)d_in[0];
    const float* n1w   = (const float*)d_in[1];
    const float* n1b   = (const float*)d_in[2];
    const float* qkvw  = (const float*)d_in[3];
    const float* qkvb  = (const float*)d_in[4];
    const float* projw = (const float*)d_in[5];
    const float* projb = (const float*)d_in[6];
    const float* n2w   = (const float*)d_in[7];
    const float* n2b   = (const float*)d_in[8];
    const float* fc1w  = (const float*)d_in[9];
    const float* fc1b  = (const float*)d_in[10];
    const float* fc2w  = (const float*)d_in[11];
    const float* fc2b  = (const float*)d_in[12];

    char* ws = (char*)d_ws;
    bf16_t* wqkv  = (bf16_t*)(ws);              // 576*192  bf16
    bf16_t* wproj = (bf16_t*)(ws + 221184);     // 192*192
    bf16_t* wfc1  = (bf16_t*)(ws + 294912);     // 768*192
    bf16_t* wfc2  = (bf16_t*)(ws + 589824);     // 192*768
    bf16_t* Xb    = (bf16_t*)(ws + 884736);     // [50176][192] bf16 (LN1 out, attn out)
    bf16_t* QKV   = (bf16_t*)(ws + 20152320);   // [50176][576] bf16
    bf16_t* Hb    = (bf16_t*)(ws + 77955072);   // [50176][768] bf16 (fc1 out)
    bf16_t* H2    = (bf16_t*)(ws + 155025408);  // [50176][192] bf16 (fc2 out)
    bf16_t* X2    = (bf16_t*)(ws + 174292992);  // [50176][192] bf16 (LN2 out)

    k_cvt<<<1728, 256, 0, stream>>>(qkvw, projw, fc1w, fc2w, wqkv);
    k_ln1<<<896, 1024, 0, stream>>>(x, n1w, n1b, Xb);
    k_gemm_1s<0, 576><<<dim3(784, 9), 256, 0, stream>>>(Xb, wqkv, qkvb, QKV);
    k_attn<<<dim3(1024, 6), 64, 0, stream>>>(QKV, Xb);
    k_proj_ln<<<784, 256, 0, stream>>>(Xb, wproj, projb, n2w, n2b, X2);
    k_gemm_1s<2, 768><<<dim3(784, 12), 256, 0, stream>>>(X2, wfc1, fc1b, Hb);
    k_gemm<0, 192, 768><<<dim3(392, 3), 256, 0, stream>>>(Hb, wfc2, fc2b, H2);
    k_final<<<896, 1024, 0, stream>>>(H2, x, (float*)d_out);
}